// Round 10
// baseline (1007.608 us; speedup 1.0000x reference)
//
#include <hip/hip_runtime.h>
#include <math.h>

#define NQ 14
#define NL 6
#define NT 512
#define NGATES (NL * NQ)
#define CHUNK 32            // amps per thread: amp = (tid<<5) | j
// amp bit p: p<5 local (register j bit p), 5<=p<11 lane bit (tid bit p-5),
//            p>=11 wave bit (tid bits 6..8). Wire w <-> amp bit P = 13-w.
// Spill control (R7..R9 lesson): the allocator caps this kernel at 128 VGPRs
// and the scheduler's 64-shuffle batching pushes peak live >128. Fix:
//  (1) amdgpu_waves_per_eu(2,2) -> budget 512/2 = 256 if honored;
//  (2) false-dependency guards (g = 0.f*ar[B+7]) bound in-flight shuffle
//      temps to one 8-amp chunk (0*x not foldable without fast-math);
//  (3) quarter-phase (8-amp) wave exchanges: 16 temp regs, barriers serialize.
// No sched_barrier anywhere (R8: it pinned liveness, 3.55 GB spill).

using F4 = float4;

// ---- prep: Rot matrices (batch-shared) into d_ws ----
// Rot(phi,theta,omega) = RZ(omega) RY(theta) RZ(phi)
__global__ void prep_kernel(const float* __restrict__ wts, float* __restrict__ gm) {
    int g = blockIdx.x * blockDim.x + threadIdx.x;
    if (g < NGATES) {
        float phi = wts[g*3+0], th = wts[g*3+1], om = wts[g*3+2];
        float c = cosf(0.5f*th), s = sinf(0.5f*th);
        float a = 0.5f*(phi+om), bb = 0.5f*(phi-om);
        float ca = cosf(a), sa = sinf(a);
        float cb = cosf(bb), sb = sinf(bb);
        gm[g*8+0] = c*ca;  gm[g*8+1] = -c*sa;   // m00
        gm[g*8+2] = -s*cb; gm[g*8+3] = -s*sb;   // m01
        gm[g*8+4] = s*cb;  gm[g*8+5] = -s*sb;   // m10
        gm[g*8+6] = c*ca;  gm[g*8+7] = c*sa;    // m11
    }
}

// ---- Rot: lo' = m00*lo + m01*hi; hi' = m10*lo + m11*hi ----
template<int P>
__device__ __forceinline__ void rot_gate(float (&ar)[CHUNK], float (&ai)[CHUNK],
                                         const float* __restrict__ m, int tid, F4* buf) {
    if constexpr (P < 5) {
        constexpr int M = 1 << P;
        float m0=m[0],m1=m[1],m2=m[2],m3=m[3],m4=m[4],m5=m[5],m6=m[6],m7=m[7];
        #pragma unroll
        for (int i = 0; i < CHUNK/2; ++i) {
            int j0 = ((i >> P) << (P+1)) | (i & (M-1));
            int j1 = j0 | M;
            float r0=ar[j0], i0=ai[j0], r1=ar[j1], i1=ai[j1];
            ar[j0] = m0*r0 - m1*i0 + m2*r1 - m3*i1;
            ai[j0] = m0*i0 + m1*r0 + m2*i1 + m3*r1;
            ar[j1] = m4*r0 - m5*i0 + m6*r1 - m7*i1;
            ai[j1] = m4*i0 + m5*r0 + m6*i1 + m7*r1;
        }
    } else if constexpr (P < 11) {
        constexpr int LM = 1 << (P-5);
        int bit = (tid >> (P-5)) & 1;
        float cAr = bit ? m[6] : m[0];
        float cAi = bit ? m[7] : m[1];
        float cBr = bit ? m[4] : m[2];
        float cBi = bit ? m[5] : m[3];
        float g = 0.f;   // false-dep guard: serializes 8-amp chunks
        #pragma unroll
        for (int B = 0; B < CHUNK; B += 8) {
            #pragma unroll
            for (int j = B; j < B+8; ++j) {
                float aj = ar[j] + g;
                float bj = ai[j] + g;
                float br = __shfl_xor(aj, LM, 64);
                float bi = __shfl_xor(bj, LM, 64);
                float nr = cAr*aj - cAi*bj + cBr*br - cBi*bi;
                float ni = cAr*bj + cAi*aj + cBr*bi + cBi*br;
                ar[j] = nr; ai[j] = ni;
            }
            g = 0.f * ar[B + 7];
        }
    } else {
        constexpr int WM = 1 << (P-5);
        int ptid = tid ^ WM;
        int bit = (tid >> (P-5)) & 1;
        float cAr = bit ? m[6] : m[0];
        float cAi = bit ? m[7] : m[1];
        float cBr = bit ? m[4] : m[2];
        float cBi = bit ? m[5] : m[3];
        // quarter phases: 8 amps (2 F4 re + 2 F4 im) per phase
        #pragma unroll
        for (int h = 0; h < 4; ++h) {
            int j = 8*h;
            buf[0*NT + tid] = make_float4(ar[j],  ar[j+1],ar[j+2],ar[j+3]);
            buf[1*NT + tid] = make_float4(ar[j+4],ar[j+5],ar[j+6],ar[j+7]);
            buf[2*NT + tid] = make_float4(ai[j],  ai[j+1],ai[j+2],ai[j+3]);
            buf[3*NT + tid] = make_float4(ai[j+4],ai[j+5],ai[j+6],ai[j+7]);
            __syncthreads();
            F4 pr0 = buf[0*NT + ptid], pr1 = buf[1*NT + ptid];
            F4 pi0 = buf[2*NT + ptid], pi1 = buf[3*NT + ptid];
            float prx[8] = {pr0.x,pr0.y,pr0.z,pr0.w, pr1.x,pr1.y,pr1.z,pr1.w};
            float pix[8] = {pi0.x,pi0.y,pi0.z,pi0.w, pi1.x,pi1.y,pi1.z,pi1.w};
            #pragma unroll
            for (int q = 0; q < 8; ++q) {
                float nr = cAr*ar[j+q] - cAi*ai[j+q] + cBr*prx[q] - cBi*pix[q];
                float ni = cAr*ai[j+q] + cAi*ar[j+q] + cBr*pix[q] + cBi*prx[q];
                ar[j+q] = nr; ai[j+q] = ni;
            }
            __syncthreads();
        }
    }
}

// ---- CNOT(ctrl bit PC, target bit PT) ----
template<int PC, int PT>
__device__ __forceinline__ void cnot_gate(float (&ar)[CHUNK], float (&ai)[CHUNK],
                                          int tid, F4* buf) {
    if constexpr (PT < 5) {
        constexpr int TM = 1 << PT;
        if constexpr (PC < 5) {
            constexpr int CM = 1 << PC;
            #pragma unroll
            for (int j = 0; j < CHUNK; ++j) {
                if ((j & CM) && !(j & TM)) {
                    int j1 = j | TM;
                    float t = ar[j]; ar[j] = ar[j1]; ar[j1] = t;
                    t = ai[j]; ai[j] = ai[j1]; ai[j1] = t;
                }
            }
        } else {
            int sel = (tid >> (PC-5)) & 1;
            #pragma unroll
            for (int i = 0; i < CHUNK/2; ++i) {
                int j0 = ((i >> PT) << (PT+1)) | (i & (TM-1));
                int j1 = j0 | TM;
                float a = ar[j0], bv = ar[j1];
                ar[j0] = sel ? bv : a; ar[j1] = sel ? a : bv;
                a = ai[j0]; bv = ai[j1];
                ai[j0] = sel ? bv : a; ai[j1] = sel ? a : bv;
            }
        }
    } else if constexpr (PT < 11) {
        constexpr int LM = 1 << (PT-5);
        if constexpr (PC < 5) {
            constexpr int CM = 1 << PC;
            float g = 0.f;
            #pragma unroll
            for (int B = 0; B < CHUNK; B += 8) {
                #pragma unroll
                for (int j = B; j < B+8; ++j) {
                    if (j & CM) {
                        ar[j] = __shfl_xor(ar[j] + g, LM, 64);
                        ai[j] = __shfl_xor(ai[j] + g, LM, 64);
                    }
                }
                if ((B + 7) & CM) g = 0.f * ar[B + 7];   // folds per unrolled iter
            }
        } else {
            int sel = (tid >> (PC-5)) & 1;
            if (sel) {  // partner differs only in PT lane bit -> same sel
                float g = 0.f;
                #pragma unroll
                for (int B = 0; B < CHUNK; B += 8) {
                    #pragma unroll
                    for (int j = B; j < B+8; ++j) {
                        ar[j] = __shfl_xor(ar[j] + g, LM, 64);
                        ai[j] = __shfl_xor(ai[j] + g, LM, 64);
                    }
                    g = 0.f * ar[B + 7];
                }
            }
        }
    } else {
        constexpr int WM = 1 << (PT-5);
        int ptid = tid ^ WM;
        if constexpr (PC < 5) {
            constexpr int CM = 1 << PC;
            // exchange the 16 ctrl==1 amps in 2 phases of 8
            #pragma unroll
            for (int h = 0; h < 2; ++h) {
                float v[16];
                #pragma unroll
                for (int q = 0; q < 8; ++q) {
                    int i = 8*h + q;
                    int j = ((i >> PC) << (PC+1)) | (i & (CM-1)) | CM;
                    v[q] = ar[j]; v[8+q] = ai[j];
                }
                buf[0*NT + tid] = make_float4(v[0], v[1], v[2], v[3]);
                buf[1*NT + tid] = make_float4(v[4], v[5], v[6], v[7]);
                buf[2*NT + tid] = make_float4(v[8], v[9], v[10],v[11]);
                buf[3*NT + tid] = make_float4(v[12],v[13],v[14],v[15]);
                __syncthreads();
                F4 pr0 = buf[0*NT + ptid], pr1 = buf[1*NT + ptid];
                F4 pi0 = buf[2*NT + ptid], pi1 = buf[3*NT + ptid];
                float prx[8] = {pr0.x,pr0.y,pr0.z,pr0.w, pr1.x,pr1.y,pr1.z,pr1.w};
                float pix[8] = {pi0.x,pi0.y,pi0.z,pi0.w, pi1.x,pi1.y,pi1.z,pi1.w};
                #pragma unroll
                for (int q = 0; q < 8; ++q) {
                    int i = 8*h + q;
                    int j = ((i >> PC) << (PC+1)) | (i & (CM-1)) | CM;
                    ar[j] = prx[q]; ai[j] = pix[q];
                }
                __syncthreads();
            }
        } else {
            // ctrl is a thread bit != PT: sel==1 threads swap whole chunk,
            // in 4 quarter phases
            int sel = (tid >> (PC-5)) & 1;
            #pragma unroll
            for (int h = 0; h < 4; ++h) {
                int j = 8*h;
                if (sel) {
                    buf[0*NT + tid] = make_float4(ar[j],  ar[j+1],ar[j+2],ar[j+3]);
                    buf[1*NT + tid] = make_float4(ar[j+4],ar[j+5],ar[j+6],ar[j+7]);
                    buf[2*NT + tid] = make_float4(ai[j],  ai[j+1],ai[j+2],ai[j+3]);
                    buf[3*NT + tid] = make_float4(ai[j+4],ai[j+5],ai[j+6],ai[j+7]);
                }
                __syncthreads();
                if (sel) {
                    F4 pr0 = buf[0*NT + ptid], pr1 = buf[1*NT + ptid];
                    F4 pi0 = buf[2*NT + ptid], pi1 = buf[3*NT + ptid];
                    ar[j]  =pr0.x; ar[j+1]=pr0.y; ar[j+2]=pr0.z; ar[j+3]=pr0.w;
                    ar[j+4]=pr1.x; ar[j+5]=pr1.y; ar[j+6]=pr1.z; ar[j+7]=pr1.w;
                    ai[j]  =pi0.x; ai[j+1]=pi0.y; ai[j+2]=pi0.z; ai[j+3]=pi0.w;
                    ai[j+4]=pi1.x; ai[j+5]=pi1.y; ai[j+6]=pi1.z; ai[j+7]=pi1.w;
                }
                __syncthreads();
            }
        }
    }
}

// ---- compile-time circuit drivers ----
template<int L, int W>
__device__ __forceinline__ void do_rots(float (&ar)[CHUNK], float (&ai)[CHUNK],
                                        const float* __restrict__ gm, int tid, F4* buf) {
    rot_gate<13-W>(ar, ai, gm + (L*NQ + W)*8, tid, buf);
    if constexpr (W < NQ-1) do_rots<L, W+1>(ar, ai, gm, tid, buf);
}

template<int L, int W>
__device__ __forceinline__ void do_cnots(float (&ar)[CHUNK], float (&ai)[CHUNK],
                                         int tid, F4* buf) {
    constexpr int R = (L % (NQ-1)) + 1;
    constexpr int TW = (W + R) % NQ;
    cnot_gate<13-W, 13-TW>(ar, ai, tid, buf);
    if constexpr (W < NQ-1) do_cnots<L, W+1>(ar, ai, tid, buf);
}

template<int L>
__device__ __forceinline__ void do_layer(float (&ar)[CHUNK], float (&ai)[CHUNK],
                                         const float* __restrict__ gm, int tid, F4* buf) {
    do_rots<L, 0>(ar, ai, gm, tid, buf);
    do_cnots<L, 0>(ar, ai, tid, buf);
    if constexpr (L < NL-1) do_layer<L+1>(ar, ai, gm, tid, buf);
}

__global__ void __launch_bounds__(NT)
__attribute__((amdgpu_waves_per_eu(2, 2)))   // budget = 512/2 = 256 VGPRs
qsim_kernel(
    const float* __restrict__ x,
    const float* __restrict__ gm,
    float* __restrict__ out)
{
    __shared__ F4 buf[4 * NT];   // static 32 KB exchange buffer
    const int tid = threadIdx.x;
    const int b = blockIdx.x;
    const float* xb = x + b * NQ;

    // ---- direct product-state init: state after RX(x_w) on |0..0> ----
    // amp(p) = prod_bits [ bit ? -i*sin(x/2) : cos(x/2) ]
    float ar[CHUNK], ai[CHUNK];
    {
        // thread-common factor over tid bits 0..8 (amp bit 5+bb, wire 8-bb)
        float cr = 1.f, ci = 0.f;
        #pragma unroll
        for (int bb = 0; bb < 9; ++bb) {
            float t = xb[8 - bb];
            float c = cosf(0.5f*t), s = sinf(0.5f*t);
            if ((tid >> bb) & 1) { float nr = s*ci, ni = -s*cr; cr = nr; ci = ni; }
            else                 { cr *= c; ci *= c; }
        }
        // local bits 0..4 (amp bit bb, wire 13-bb)
        float lc[5], ls[5];
        #pragma unroll
        for (int bb = 0; bb < 5; ++bb) {
            float t = xb[13 - bb];
            lc[bb] = cosf(0.5f*t); ls[bb] = sinf(0.5f*t);
        }
        #pragma unroll
        for (int j = 0; j < CHUNK; ++j) {
            float rr = cr, ii = ci;
            #pragma unroll
            for (int bb = 0; bb < 5; ++bb) {
                if ((j >> bb) & 1) { float nr = ls[bb]*ii, ni = -ls[bb]*rr; rr = nr; ii = ni; }
                else               { rr *= lc[bb]; ii *= lc[bb]; }
            }
            ar[j] = rr; ai[j] = ii;
        }
    }
    __syncthreads();

    do_layer<0>(ar, ai, gm, tid, buf);

    // <Z0>: amp bit 13 = tid bit 8 -> sign uniform per thread
    float acc = 0.f;
    #pragma unroll
    for (int j = 0; j < CHUNK; ++j) acc += ar[j]*ar[j] + ai[j]*ai[j];
    if (tid & 256) acc = -acc;
    #pragma unroll
    for (int off = 32; off > 0; off >>= 1) acc += __shfl_down(acc, off, 64);
    __syncthreads();
    float* f = (float*)buf;
    if ((tid & 63) == 0) f[tid >> 6] = acc;
    __syncthreads();
    if (tid == 0) {
        float s = 0.f;
        #pragma unroll
        for (int w = 0; w < NT/64; ++w) s += f[w];
        out[b] = s;
    }
}

extern "C" void kernel_launch(void* const* d_in, const int* in_sizes, int n_in,
                              void* d_out, int out_size, void* d_ws, size_t ws_size,
                              hipStream_t stream) {
    const float* x = (const float*)d_in[0];   // (1024, 14) float32
    const float* w = (const float*)d_in[1];   // (6, 14, 3) float32
    float* out = (float*)d_out;               // (1024,) float32
    float* gm = (float*)d_ws;                 // 84*8 floats of Rot matrices

    prep_kernel<<<1, 128, 0, stream>>>(w, gm);
    qsim_kernel<<<out_size, NT, 0, stream>>>(x, gm, out);
}

// Round 11
// 971.641 us; speedup vs baseline: 1.0370x; 1.0370x over previous
//
#include <hip/hip_runtime.h>
#include <math.h>

#define NQ 14
#define NL 6
#define NT 512
#define NGATES (NL * NQ)
#define CHUNK 32            // amps per thread: amp = (tid<<5) | j
// amp bit p: p<5 local (register j bit p), 5<=p<11 lane bit (tid bit p-5),
//            p>=11 wave bit (tid bits 6..8). Wire w <-> amp bit P = 13-w.
// Spill control (R7..R10): allocator pins VGPR budget at 128 for NT=512 and
// every budget-raise knob (launch_bounds min-waves, waves_per_eu, static LDS)
// is ignored. So demand must stay < 128: false-dependency guards
// (g = 0.f * ar[..], not foldable without fast-math) bound the scheduler's
// in-flight window to 8 amps in EVERY multi-amp gate body (shuffle gates,
// local rot gates, sel-CNOTs), and wave exchanges run in 8-amp quarter
// phases. Peak live ~= 64 state + ~16 temps + coeffs < 128.
// No sched_barrier (R8: pinned liveness, made spill worse).

using F4 = float4;

// ---- prep: Rot matrices (batch-shared) into d_ws ----
// Rot(phi,theta,omega) = RZ(omega) RY(theta) RZ(phi)
__global__ void prep_kernel(const float* __restrict__ wts, float* __restrict__ gm) {
    int g = blockIdx.x * blockDim.x + threadIdx.x;
    if (g < NGATES) {
        float phi = wts[g*3+0], th = wts[g*3+1], om = wts[g*3+2];
        float c = cosf(0.5f*th), s = sinf(0.5f*th);
        float a = 0.5f*(phi+om), bb = 0.5f*(phi-om);
        float ca = cosf(a), sa = sinf(a);
        float cb = cosf(bb), sb = sinf(bb);
        gm[g*8+0] = c*ca;  gm[g*8+1] = -c*sa;   // m00
        gm[g*8+2] = -s*cb; gm[g*8+3] = -s*sb;   // m01
        gm[g*8+4] = s*cb;  gm[g*8+5] = -s*sb;   // m10
        gm[g*8+6] = c*ca;  gm[g*8+7] = c*sa;    // m11
    }
}

// ---- Rot: lo' = m00*lo + m01*hi; hi' = m10*lo + m11*hi ----
template<int P>
__device__ __forceinline__ void rot_gate(float (&ar)[CHUNK], float (&ai)[CHUNK],
                                         const float* __restrict__ m, int tid, F4* buf) {
    if constexpr (P < 5) {
        constexpr int M = 1 << P;
        float m0=m[0],m1=m[1],m2=m[2],m3=m[3],m4=m[4],m5=m[5],m6=m[6],m7=m[7];
        float g = 0.f;   // false-dep guard: bounds in-flight pairs to 4
        #pragma unroll
        for (int B = 0; B < CHUNK/2; B += 4) {
            #pragma unroll
            for (int i = B; i < B+4; ++i) {
                int j0 = ((i >> P) << (P+1)) | (i & (M-1));
                int j1 = j0 | M;
                float r0=ar[j0]+g, i0=ai[j0]+g, r1=ar[j1], i1=ai[j1];
                ar[j0] = m0*r0 - m1*i0 + m2*r1 - m3*i1;
                ai[j0] = m0*i0 + m1*r0 + m2*i1 + m3*r1;
                ar[j1] = m4*r0 - m5*i0 + m6*r1 - m7*i1;
                ai[j1] = m4*i0 + m5*r0 + m6*i1 + m7*r1;
            }
            {
                int last = ((B+3) >> P << (P+1)) | ((B+3) & (M-1));
                g = 0.f * ar[last];
            }
        }
    } else if constexpr (P < 11) {
        constexpr int LM = 1 << (P-5);
        int bit = (tid >> (P-5)) & 1;
        float cAr = bit ? m[6] : m[0];
        float cAi = bit ? m[7] : m[1];
        float cBr = bit ? m[4] : m[2];
        float cBi = bit ? m[5] : m[3];
        float g = 0.f;   // false-dep guard: serializes 8-amp chunks
        #pragma unroll
        for (int B = 0; B < CHUNK; B += 8) {
            #pragma unroll
            for (int j = B; j < B+8; ++j) {
                float aj = ar[j] + g;
                float bj = ai[j] + g;
                float br = __shfl_xor(aj, LM, 64);
                float bi = __shfl_xor(bj, LM, 64);
                float nr = cAr*aj - cAi*bj + cBr*br - cBi*bi;
                float ni = cAr*bj + cAi*aj + cBr*bi + cBi*br;
                ar[j] = nr; ai[j] = ni;
            }
            g = 0.f * ar[B + 7];
        }
    } else {
        constexpr int WM = 1 << (P-5);
        int ptid = tid ^ WM;
        int bit = (tid >> (P-5)) & 1;
        float cAr = bit ? m[6] : m[0];
        float cAi = bit ? m[7] : m[1];
        float cBr = bit ? m[4] : m[2];
        float cBi = bit ? m[5] : m[3];
        // quarter phases: 8 amps (2 F4 re + 2 F4 im) per phase
        #pragma unroll
        for (int h = 0; h < 4; ++h) {
            int j = 8*h;
            buf[0*NT + tid] = make_float4(ar[j],  ar[j+1],ar[j+2],ar[j+3]);
            buf[1*NT + tid] = make_float4(ar[j+4],ar[j+5],ar[j+6],ar[j+7]);
            buf[2*NT + tid] = make_float4(ai[j],  ai[j+1],ai[j+2],ai[j+3]);
            buf[3*NT + tid] = make_float4(ai[j+4],ai[j+5],ai[j+6],ai[j+7]);
            __syncthreads();
            F4 pr0 = buf[0*NT + ptid], pr1 = buf[1*NT + ptid];
            F4 pi0 = buf[2*NT + ptid], pi1 = buf[3*NT + ptid];
            float prx[8] = {pr0.x,pr0.y,pr0.z,pr0.w, pr1.x,pr1.y,pr1.z,pr1.w};
            float pix[8] = {pi0.x,pi0.y,pi0.z,pi0.w, pi1.x,pi1.y,pi1.z,pi1.w};
            #pragma unroll
            for (int q = 0; q < 8; ++q) {
                float nr = cAr*ar[j+q] - cAi*ai[j+q] + cBr*prx[q] - cBi*pix[q];
                float ni = cAr*ai[j+q] + cAi*ar[j+q] + cBr*pix[q] + cBi*prx[q];
                ar[j+q] = nr; ai[j+q] = ni;
            }
            __syncthreads();
        }
    }
}

// ---- CNOT(ctrl bit PC, target bit PT) ----
template<int PC, int PT>
__device__ __forceinline__ void cnot_gate(float (&ar)[CHUNK], float (&ai)[CHUNK],
                                          int tid, F4* buf) {
    if constexpr (PT < 5) {
        constexpr int TM = 1 << PT;
        if constexpr (PC < 5) {
            constexpr int CM = 1 << PC;
            // pure register permutation; compiler renames, no pressure
            #pragma unroll
            for (int j = 0; j < CHUNK; ++j) {
                if ((j & CM) && !(j & TM)) {
                    int j1 = j | TM;
                    float t = ar[j]; ar[j] = ar[j1]; ar[j1] = t;
                    t = ai[j]; ai[j] = ai[j1]; ai[j1] = t;
                }
            }
        } else {
            int sel = (tid >> (PC-5)) & 1;
            float g = 0.f;   // guard: 4 pairs in flight
            #pragma unroll
            for (int B = 0; B < CHUNK/2; B += 4) {
                #pragma unroll
                for (int i = B; i < B+4; ++i) {
                    int j0 = ((i >> PT) << (PT+1)) | (i & (TM-1));
                    int j1 = j0 | TM;
                    float a = ar[j0]+g, bv = ar[j1];
                    ar[j0] = sel ? bv : a; ar[j1] = sel ? a : bv;
                    a = ai[j0]; bv = ai[j1];
                    ai[j0] = sel ? bv : a; ai[j1] = sel ? a : bv;
                }
                {
                    int last = ((B+3) >> PT << (PT+1)) | ((B+3) & (TM-1));
                    g = 0.f * ar[last];
                }
            }
        }
    } else if constexpr (PT < 11) {
        constexpr int LM = 1 << (PT-5);
        if constexpr (PC < 5) {
            constexpr int CM = 1 << PC;
            float g = 0.f;
            #pragma unroll
            for (int B = 0; B < CHUNK; B += 8) {
                #pragma unroll
                for (int j = B; j < B+8; ++j) {
                    if (j & CM) {
                        ar[j] = __shfl_xor(ar[j] + g, LM, 64);
                        ai[j] = __shfl_xor(ai[j] + g, LM, 64);
                    }
                }
                if ((B + 7) & CM) g = 0.f * ar[B + 7];
            }
        } else {
            int sel = (tid >> (PC-5)) & 1;
            if (sel) {  // partner differs only in PT lane bit -> same sel
                float g = 0.f;
                #pragma unroll
                for (int B = 0; B < CHUNK; B += 8) {
                    #pragma unroll
                    for (int j = B; j < B+8; ++j) {
                        ar[j] = __shfl_xor(ar[j] + g, LM, 64);
                        ai[j] = __shfl_xor(ai[j] + g, LM, 64);
                    }
                    g = 0.f * ar[B + 7];
                }
            }
        }
    } else {
        constexpr int WM = 1 << (PT-5);
        int ptid = tid ^ WM;
        if constexpr (PC < 5) {
            constexpr int CM = 1 << PC;
            // exchange the 16 ctrl==1 amps in 2 phases of 8
            #pragma unroll
            for (int h = 0; h < 2; ++h) {
                float v[16];
                #pragma unroll
                for (int q = 0; q < 8; ++q) {
                    int i = 8*h + q;
                    int j = ((i >> PC) << (PC+1)) | (i & (CM-1)) | CM;
                    v[q] = ar[j]; v[8+q] = ai[j];
                }
                buf[0*NT + tid] = make_float4(v[0], v[1], v[2], v[3]);
                buf[1*NT + tid] = make_float4(v[4], v[5], v[6], v[7]);
                buf[2*NT + tid] = make_float4(v[8], v[9], v[10],v[11]);
                buf[3*NT + tid] = make_float4(v[12],v[13],v[14],v[15]);
                __syncthreads();
                F4 pr0 = buf[0*NT + ptid], pr1 = buf[1*NT + ptid];
                F4 pi0 = buf[2*NT + ptid], pi1 = buf[3*NT + ptid];
                float prx[8] = {pr0.x,pr0.y,pr0.z,pr0.w, pr1.x,pr1.y,pr1.z,pr1.w};
                float pix[8] = {pi0.x,pi0.y,pi0.z,pi0.w, pi1.x,pi1.y,pi1.z,pi1.w};
                #pragma unroll
                for (int q = 0; q < 8; ++q) {
                    int i = 8*h + q;
                    int j = ((i >> PC) << (PC+1)) | (i & (CM-1)) | CM;
                    ar[j] = prx[q]; ai[j] = pix[q];
                }
                __syncthreads();
            }
        } else {
            // ctrl is a thread bit != PT: sel==1 threads swap whole chunk,
            // in 4 quarter phases
            int sel = (tid >> (PC-5)) & 1;
            #pragma unroll
            for (int h = 0; h < 4; ++h) {
                int j = 8*h;
                if (sel) {
                    buf[0*NT + tid] = make_float4(ar[j],  ar[j+1],ar[j+2],ar[j+3]);
                    buf[1*NT + tid] = make_float4(ar[j+4],ar[j+5],ar[j+6],ar[j+7]);
                    buf[2*NT + tid] = make_float4(ai[j],  ai[j+1],ai[j+2],ai[j+3]);
                    buf[3*NT + tid] = make_float4(ai[j+4],ai[j+5],ai[j+6],ai[j+7]);
                }
                __syncthreads();
                if (sel) {
                    F4 pr0 = buf[0*NT + ptid], pr1 = buf[1*NT + ptid];
                    F4 pi0 = buf[2*NT + ptid], pi1 = buf[3*NT + ptid];
                    ar[j]  =pr0.x; ar[j+1]=pr0.y; ar[j+2]=pr0.z; ar[j+3]=pr0.w;
                    ar[j+4]=pr1.x; ar[j+5]=pr1.y; ar[j+6]=pr1.z; ar[j+7]=pr1.w;
                    ai[j]  =pi0.x; ai[j+1]=pi0.y; ai[j+2]=pi0.z; ai[j+3]=pi0.w;
                    ai[j+4]=pi1.x; ai[j+5]=pi1.y; ai[j+6]=pi1.z; ai[j+7]=pi1.w;
                }
                __syncthreads();
            }
        }
    }
}

// ---- compile-time circuit drivers ----
template<int L, int W>
__device__ __forceinline__ void do_rots(float (&ar)[CHUNK], float (&ai)[CHUNK],
                                        const float* __restrict__ gm, int tid, F4* buf) {
    rot_gate<13-W>(ar, ai, gm + (L*NQ + W)*8, tid, buf);
    if constexpr (W < NQ-1) do_rots<L, W+1>(ar, ai, gm, tid, buf);
}

template<int L, int W>
__device__ __forceinline__ void do_cnots(float (&ar)[CHUNK], float (&ai)[CHUNK],
                                         int tid, F4* buf) {
    constexpr int R = (L % (NQ-1)) + 1;
    constexpr int TW = (W + R) % NQ;
    cnot_gate<13-W, 13-TW>(ar, ai, tid, buf);
    if constexpr (W < NQ-1) do_cnots<L, W+1>(ar, ai, tid, buf);
}

template<int L>
__device__ __forceinline__ void do_layer(float (&ar)[CHUNK], float (&ai)[CHUNK],
                                         const float* __restrict__ gm, int tid, F4* buf) {
    do_rots<L, 0>(ar, ai, gm, tid, buf);
    do_cnots<L, 0>(ar, ai, tid, buf);
    if constexpr (L < NL-1) do_layer<L+1>(ar, ai, gm, tid, buf);
}

__global__ void __launch_bounds__(NT)
qsim_kernel(
    const float* __restrict__ x,
    const float* __restrict__ gm,
    float* __restrict__ out)
{
    __shared__ F4 buf[4 * NT];   // static 32 KB; 2 blocks/CU at 128 VGPRs
    const int tid = threadIdx.x;
    const int b = blockIdx.x;
    const float* xb = x + b * NQ;

    // ---- direct product-state init: state after RX(x_w) on |0..0> ----
    // amp(p) = prod_bits [ bit ? -i*sin(x/2) : cos(x/2) ]
    float ar[CHUNK], ai[CHUNK];
    {
        // thread-common factor over tid bits 0..8 (amp bit 5+bb, wire 8-bb)
        float cr = 1.f, ci = 0.f;
        #pragma unroll
        for (int bb = 0; bb < 9; ++bb) {
            float t = xb[8 - bb];
            float c = cosf(0.5f*t), s = sinf(0.5f*t);
            if ((tid >> bb) & 1) { float nr = s*ci, ni = -s*cr; cr = nr; ci = ni; }
            else                 { cr *= c; ci *= c; }
        }
        // local bits 0..4 (amp bit bb, wire 13-bb)
        float lc[5], ls[5];
        #pragma unroll
        for (int bb = 0; bb < 5; ++bb) {
            float t = xb[13 - bb];
            lc[bb] = cosf(0.5f*t); ls[bb] = sinf(0.5f*t);
        }
        float g = 0.f;
        #pragma unroll
        for (int B = 0; B < CHUNK; B += 8) {
            #pragma unroll
            for (int j = B; j < B+8; ++j) {
                float rr = cr + g, ii = ci;
                #pragma unroll
                for (int bb = 0; bb < 5; ++bb) {
                    if ((j >> bb) & 1) { float nr = ls[bb]*ii, ni = -ls[bb]*rr; rr = nr; ii = ni; }
                    else               { rr *= lc[bb]; ii *= lc[bb]; }
                }
                ar[j] = rr; ai[j] = ii;
            }
            g = 0.f * ar[B + 7];
        }
    }
    __syncthreads();

    do_layer<0>(ar, ai, gm, tid, buf);

    // <Z0>: amp bit 13 = tid bit 8 -> sign uniform per thread
    float acc = 0.f;
    #pragma unroll
    for (int j = 0; j < CHUNK; ++j) acc += ar[j]*ar[j] + ai[j]*ai[j];
    if (tid & 256) acc = -acc;
    #pragma unroll
    for (int off = 32; off > 0; off >>= 1) acc += __shfl_down(acc, off, 64);
    __syncthreads();
    float* f = (float*)buf;
    if ((tid & 63) == 0) f[tid >> 6] = acc;
    __syncthreads();
    if (tid == 0) {
        float s = 0.f;
        #pragma unroll
        for (int w = 0; w < NT/64; ++w) s += f[w];
        out[b] = s;
    }
}

extern "C" void kernel_launch(void* const* d_in, const int* in_sizes, int n_in,
                              void* d_out, int out_size, void* d_ws, size_t ws_size,
                              hipStream_t stream) {
    const float* x = (const float*)d_in[0];   // (1024, 14) float32
    const float* w = (const float*)d_in[1];   // (6, 14, 3) float32
    float* out = (float*)d_out;               // (1024,) float32
    float* gm = (float*)d_ws;                 // 84*8 floats of Rot matrices

    prep_kernel<<<1, 128, 0, stream>>>(w, gm);
    qsim_kernel<<<out_size, NT, 0, stream>>>(x, gm, out);
}